// Round 1
// 200.668 us; speedup vs baseline: 1.0463x; 1.0463x over previous
//
#include <hip/hip_runtime.h>

#define NN    100000   // N_NODES
#define F     64       // feature dim (= hidden dim)
#define NBUCK 391      // ceil(NN/256) buckets of 256 nodes
#define CAPB  4096     // per-bucket edge capacity (mean 3197, 16-sigma margin)
#define TILE  4096     // edges per binpack tile
#define G1A   1600     // gemm1 blocks placed in K1 (rest overlap node_sort in K2)
#define G1TOT 3125     // NN/32 total gemm1 blocks

// workspace offsets (4-byte elements)
#define O_CURSOR 0          // int[391]
#define O_ROWPTR 512        // int[100000]  absolute index into srt
#define O_DEG    100864     // int[100000]
#define O_DIS    201216     // float[100000]
#define O_PACKED 301568     // uint[391*4096]
#define O_SRT    1903104    // int[391*4096 + 64]
#define O_AH     3504768    // uint[NN*32]: bf16-packed layer-1 A rows (128 B/row)
#define O_BH     6704768    // uint[NN*32]: bf16-packed layer-2 A rows (h @ W2)

// ---- bf16 pack/unpack (RNE; values finite) --------------------------------
__device__ __forceinline__ unsigned bf_rne(float x) {
    unsigned u = __float_as_uint(x);
    return (u + 0x7FFFu + ((u >> 16) & 1u)) >> 16;
}
__device__ __forceinline__ unsigned pack2(float lo, float hi) {
    return bf_rne(lo) | (bf_rne(hi) << 16);
}
__device__ __forceinline__ float lo_f(unsigned u) { return __uint_as_float(u << 16); }
__device__ __forceinline__ float hi_f(unsigned u) { return __uint_as_float(u & 0xFFFF0000u); }

// ---- shared-memory unions (per-block exclusive) ----------------------------
struct BpSmem {
    int hist[NBUCK], lofs[NBUCK], gbase[NBUCK], lcur[NBUCK];
    int wsum[8];
    unsigned stage[TILE];                     // 16 KB
    unsigned short sbuck[TILE];               // 8 KB
};                                            // 30864 B
union KSmem {
    BpSmem bp;
    float wl[64 * 64];                        // 16 KB
};
struct NsSmem {
    int h[256], lcur[256], wsum[4];
    int stage[CAPB];                          // 16 KB
};                                            // 18448 B
union K2Smem {
    NsSmem ns;
    float wl[64 * 64];                        // 16 KB
};

// ---------------------------------------------------------------------------
// binpack body: tile counting-sort into 391 bucket-strided regions (one
// global atomic per bucket per tile at implicit base b*CAPB).
// packed = (src<<8) | (dst & 255). 512 threads.
// ---------------------------------------------------------------------------
__device__ __forceinline__ void binpack_body(const int* __restrict__ src,
                                             const int* __restrict__ dst, int E,
                                             int* __restrict__ cursor,
                                             unsigned* __restrict__ packed,
                                             int bid, BpSmem& sm) {
    int t  = threadIdx.x;
    int t0 = bid * TILE;
    int n  = min(TILE, E - t0);

    if (t < NBUCK) sm.hist[t] = 0;
    __syncthreads();
    for (int i = t; i < n; i += 512) atomicAdd(&sm.hist[dst[t0 + i] >> 8], 1);
    __syncthreads();
    int lane = t & 63, w = t >> 6;
    int v = (t < NBUCK) ? sm.hist[t] : 0;
    int s = v;
#pragma unroll
    for (int off = 1; off < 64; off <<= 1) {
        int u = __shfl_up(s, off, 64);
        if (lane >= off) s += u;
    }
    if (lane == 63) sm.wsum[w] = s;
    __syncthreads();
    if (t == 0) {
        int run = 0;
#pragma unroll
        for (int i = 0; i < 8; ++i) { int c = sm.wsum[i]; sm.wsum[i] = run; run += c; }
    }
    __syncthreads();
    if (t < NBUCK) {
        int ex = s - v + sm.wsum[w];
        sm.lofs[t] = ex;
        sm.lcur[t] = ex;
        sm.gbase[t] = t * CAPB + (v ? atomicAdd(&cursor[t], v) : 0);
    }
    __syncthreads();
    for (int i = t; i < n; i += 512) {
        int d = dst[t0 + i];
        int b = d >> 8;
        int p = atomicAdd(&sm.lcur[b], 1);
        sm.stage[p] = ((unsigned)src[t0 + i] << 8) | (unsigned)(d & 255);
        sm.sbuck[p] = (unsigned short)b;
    }
    __syncthreads();
    for (int i = t; i < n; i += 512) {
        int b = sm.sbuck[i];
        packed[sm.gbase[b] + (i - sm.lofs[b])] = sm.stage[i];
    }
}

// ---------------------------------------------------------------------------
// gemm body (f32 X): Ah = bf16(X @ W). VALU loop, x broadcast via readlane.
// 512 thr = 8 waves x 4 rows = 32 rows/block. Even lanes pack col pairs.
// ---------------------------------------------------------------------------
__device__ __forceinline__ void gemm_body(const float* __restrict__ X,
                                          const float* __restrict__ W,
                                          unsigned* __restrict__ Ah, int bid,
                                          float* wl) {
    int t = threadIdx.x;
    for (int i = t; i < 64 * 64; i += 512) wl[i] = W[i];
    __syncthreads();
    int lane = t & 63;
    int w    = t >> 6;
    float Wreg[64];
#pragma unroll
    for (int k = 0; k < 64; ++k) Wreg[k] = wl[k * 64 + lane];

    int row0 = bid * 32 + w * 4;
    const float* xp = X + (size_t)row0 * F;
    float xa = xp[lane];
    float xb = xp[64 + lane];
    float xc = xp[128 + lane];
    float xd = xp[192 + lane];
    float a0 = 0.f, a1 = 0.f, a2 = 0.f, a3 = 0.f;
#pragma unroll
    for (int k = 0; k < 64; ++k) {
        float wv = Wreg[k];
        a0 = fmaf(__uint_as_float(__builtin_amdgcn_readlane(__float_as_uint(xa), k)), wv, a0);
        a1 = fmaf(__uint_as_float(__builtin_amdgcn_readlane(__float_as_uint(xb), k)), wv, a1);
        a2 = fmaf(__uint_as_float(__builtin_amdgcn_readlane(__float_as_uint(xc), k)), wv, a2);
        a3 = fmaf(__uint_as_float(__builtin_amdgcn_readlane(__float_as_uint(xd), k)), wv, a3);
    }
    float p0 = __shfl_xor(a0, 1, 64);
    float p1 = __shfl_xor(a1, 1, 64);
    float p2 = __shfl_xor(a2, 1, 64);
    float p3 = __shfl_xor(a3, 1, 64);
    if (!(lane & 1)) {
        int c = lane >> 1;
        Ah[(size_t)(row0 + 0) * 32 + c] = pack2(a0, p0);
        Ah[(size_t)(row0 + 1) * 32 + c] = pack2(a1, p1);
        Ah[(size_t)(row0 + 2) * 32 + c] = pack2(a2, p2);
        Ah[(size_t)(row0 + 3) * 32 + c] = pack2(a3, p3);
    }
}

// ---------------------------------------------------------------------------
// node_sort body: per-bucket LDS counting sort to node order; emits row_ptr
// (absolute), deg, dis = rsqrt(deg+1). srt stays bucket-strided.
// ---------------------------------------------------------------------------
__device__ __forceinline__ void node_sort_body(const unsigned* __restrict__ packed,
                                               const int* __restrict__ cursor,
                                               int* __restrict__ row_ptr,
                                               int* __restrict__ deg,
                                               float* __restrict__ dis,
                                               int* __restrict__ srt,
                                               int b, NsSmem& sm) {
    int t = threadIdx.x;
    int nbase = b << 8;
    int nloc = min(256, NN - nbase);
    int beg = b * CAPB;
    int n = cursor[b];

    if (t < 256) sm.h[t] = 0;
    __syncthreads();
    for (int i = t; i < n; i += 512)
        atomicAdd(&sm.h[packed[beg + i] & 255u], 1);
    __syncthreads();
    int lane = t & 63, w = t >> 6;
    int v = 0, s = 0;
    if (t < 256) { v = sm.h[t]; s = v; }
#pragma unroll
    for (int off = 1; off < 64; off <<= 1) {
        int u = __shfl_up(s, off, 64);
        if (lane >= off) s += u;
    }
    if (t < 256 && lane == 63) sm.wsum[w] = s;
    __syncthreads();
    if (t == 0) {
        int run = 0;
#pragma unroll
        for (int i = 0; i < 4; ++i) { int c = sm.wsum[i]; sm.wsum[i] = run; run += c; }
    }
    __syncthreads();
    if (t < 256) {
        int e0 = s - v + sm.wsum[w];
        sm.lcur[t] = e0;
        if (t < nloc) {
            row_ptr[nbase + t] = beg + e0;
            deg[nbase + t]     = v;
            dis[nbase + t]     = rsqrtf((float)v + 1.0f);   // +1 = self-loop
        }
    }
    __syncthreads();
    for (int i = t; i < n; i += 512) {
        unsigned p = packed[beg + i];
        int pos = atomicAdd(&sm.lcur[p & 255u], 1);
        sm.stage[pos] = (int)(p >> 8);
    }
    __syncthreads();
    for (int i = t; i < n; i += 512) srt[beg + i] = sm.stage[i];
}

// K1: binpack (blocks [0,nbp)) || layer-1 gemm part A (rest). LDS = union.
__global__ __launch_bounds__(512) void pre_gemm1(const int* __restrict__ src,
                                                 const int* __restrict__ dst, int E,
                                                 int nbp, int* __restrict__ cursor,
                                                 unsigned* __restrict__ packed,
                                                 const float* __restrict__ X,
                                                 const float* __restrict__ W1,
                                                 unsigned* __restrict__ Ah) {
    __shared__ KSmem sm;
    if ((int)blockIdx.x < nbp)
        binpack_body(src, dst, E, cursor, packed, blockIdx.x, sm.bp);
    else
        gemm_body(X, W1, Ah, (int)blockIdx.x - nbp, sm.wl);
}

// K2: node_sort (blocks [0,NBUCK)) || layer-1 gemm part B (rest).
__global__ __launch_bounds__(512) void sort_gemm1(const unsigned* __restrict__ packed,
                                                  const int* __restrict__ cursor,
                                                  int* __restrict__ row_ptr,
                                                  int* __restrict__ deg,
                                                  float* __restrict__ dis,
                                                  int* __restrict__ srt,
                                                  const float* __restrict__ X,
                                                  const float* __restrict__ W1,
                                                  unsigned* __restrict__ Ah) {
    __shared__ K2Smem sm;
    if ((int)blockIdx.x < NBUCK)
        node_sort_body(packed, cursor, row_ptr, deg, dis, srt, blockIdx.x, sm.ns);
    else
        gemm_body(X, W1, Ah, G1A + (int)blockIdx.x - NBUCK, sm.wl);
}

// ---------------------------------------------------------------------------
// K3: layer-1 aggregate (gather over bf16 A, dis scaling, +b1, ReLU) fused
// with layer-2 transform h @ W2 -> bf16 Bh. 16 lanes/node, 16 nodes/block.
// Epilogue: lane owns output col = lane for its wave's 4 nodes; h broadcast
// via readlane of the packed bf16 pair held by lane n*16 + (k>>2). FLOP
// order identical to the old Hh->gemm2h path => bitwise-identical output.
// ---------------------------------------------------------------------------
__global__ __launch_bounds__(256) void agg1_gemm2(const uint2* __restrict__ Ah2,
                                                  const int* __restrict__ row_ptr,
                                                  const int* __restrict__ deg,
                                                  const int* __restrict__ srt,
                                                  const float* __restrict__ dis,
                                                  const float* __restrict__ b1,
                                                  const float* __restrict__ W2,
                                                  unsigned* __restrict__ Bh) {
    __shared__ float wl[64 * 64];                 // W2 staged once per block
    int t = threadIdx.x;
    for (int i = t; i < 64 * 64; i += 256) wl[i] = W2[i];
    __syncthreads();

    int sub  = t & 15;
    int node = blockIdx.x * 16 + (t >> 4);
    int beg = row_ptr[node];
    int end = beg + deg[node];
    float di = dis[node];
    uint2 su = Ah2[(size_t)node * 16 + sub];
    float4 acc;
    acc.x = di * lo_f(su.x);
    acc.y = di * hi_f(su.x);
    acc.z = di * lo_f(su.y);
    acc.w = di * hi_f(su.y);
    int j = beg;
    for (; j + 4 <= end; j += 4) {
        int s0 = srt[j], s1 = srt[j + 1], s2 = srt[j + 2], s3 = srt[j + 3];
        float d0 = dis[s0], d1 = dis[s1], d2 = dis[s2], d3 = dis[s3];
        uint2 g0 = Ah2[(size_t)s0 * 16 + sub];
        uint2 g1 = Ah2[(size_t)s1 * 16 + sub];
        uint2 g2 = Ah2[(size_t)s2 * 16 + sub];
        uint2 g3 = Ah2[(size_t)s3 * 16 + sub];
        acc.x = fmaf(d0, lo_f(g0.x), fmaf(d1, lo_f(g1.x), fmaf(d2, lo_f(g2.x), fmaf(d3, lo_f(g3.x), acc.x))));
        acc.y = fmaf(d0, hi_f(g0.x), fmaf(d1, hi_f(g1.x), fmaf(d2, hi_f(g2.x), fmaf(d3, hi_f(g3.x), acc.y))));
        acc.z = fmaf(d0, lo_f(g0.y), fmaf(d1, lo_f(g1.y), fmaf(d2, lo_f(g2.y), fmaf(d3, lo_f(g3.y), acc.z))));
        acc.w = fmaf(d0, hi_f(g0.y), fmaf(d1, hi_f(g1.y), fmaf(d2, hi_f(g2.y), fmaf(d3, hi_f(g3.y), acc.w))));
    }
    for (; j < end; ++j) {
        int s0 = srt[j];
        float d0 = dis[s0];
        uint2 g0 = Ah2[(size_t)s0 * 16 + sub];
        acc.x = fmaf(d0, lo_f(g0.x), acc.x);
        acc.y = fmaf(d0, hi_f(g0.x), acc.y);
        acc.z = fmaf(d0, lo_f(g0.y), acc.z);
        acc.w = fmaf(d0, hi_f(g0.y), acc.w);
    }
    float4 bb = ((const float4*)b1)[sub];
    float4 o;
    o.x = fmaxf(fmaf(di, acc.x, bb.x), 0.f);
    o.y = fmaxf(fmaf(di, acc.y, bb.y), 0.f);
    o.z = fmaxf(fmaf(di, acc.z, bb.z), 0.f);
    o.w = fmaxf(fmaf(di, acc.w, bb.w), 0.f);
    // lane sub holds h[node][4*sub .. 4*sub+3] packed as bf16 pairs
    unsigned pkx = pack2(o.x, o.y);
    unsigned pky = pack2(o.z, o.w);

    // ---- fused h @ W2: lane = output col, nodes 0..3 of this wave ----------
    int lane = t & 63;
    float a0 = 0.f, a1 = 0.f, a2 = 0.f, a3 = 0.f;
#pragma unroll
    for (int kq = 0; kq < 16; ++kq) {
        float w0 = wl[(4 * kq + 0) * 64 + lane];
        float w1 = wl[(4 * kq + 1) * 64 + lane];
        float w2 = wl[(4 * kq + 2) * 64 + lane];
        float w3 = wl[(4 * kq + 3) * 64 + lane];
        unsigned qx0 = __builtin_amdgcn_readlane(pkx, kq);
        unsigned qy0 = __builtin_amdgcn_readlane(pky, kq);
        unsigned qx1 = __builtin_amdgcn_readlane(pkx, 16 + kq);
        unsigned qy1 = __builtin_amdgcn_readlane(pky, 16 + kq);
        unsigned qx2 = __builtin_amdgcn_readlane(pkx, 32 + kq);
        unsigned qy2 = __builtin_amdgcn_readlane(pky, 32 + kq);
        unsigned qx3 = __builtin_amdgcn_readlane(pkx, 48 + kq);
        unsigned qy3 = __builtin_amdgcn_readlane(pky, 48 + kq);
        a0 = fmaf(lo_f(qx0), w0, a0); a0 = fmaf(hi_f(qx0), w1, a0);
        a0 = fmaf(lo_f(qy0), w2, a0); a0 = fmaf(hi_f(qy0), w3, a0);
        a1 = fmaf(lo_f(qx1), w0, a1); a1 = fmaf(hi_f(qx1), w1, a1);
        a1 = fmaf(lo_f(qy1), w2, a1); a1 = fmaf(hi_f(qy1), w3, a1);
        a2 = fmaf(lo_f(qx2), w0, a2); a2 = fmaf(hi_f(qx2), w1, a2);
        a2 = fmaf(lo_f(qy2), w2, a2); a2 = fmaf(hi_f(qy2), w3, a2);
        a3 = fmaf(lo_f(qx3), w0, a3); a3 = fmaf(hi_f(qx3), w1, a3);
        a3 = fmaf(lo_f(qy3), w2, a3); a3 = fmaf(hi_f(qy3), w3, a3);
    }
    float p0 = __shfl_xor(a0, 1, 64);
    float p1 = __shfl_xor(a1, 1, 64);
    float p2 = __shfl_xor(a2, 1, 64);
    float p3 = __shfl_xor(a3, 1, 64);
    if (!(lane & 1)) {
        int c = lane >> 1;
        int row0 = blockIdx.x * 16 + (t >> 6) * 4;
        Bh[(size_t)(row0 + 0) * 32 + c] = pack2(a0, p0);
        Bh[(size_t)(row0 + 1) * 32 + c] = pack2(a1, p1);
        Bh[(size_t)(row0 + 2) * 32 + c] = pack2(a2, p2);
        Bh[(size_t)(row0 + 3) * 32 + c] = pack2(a3, p3);
    }
}

// ---------------------------------------------------------------------------
// K4: layer-2 aggregate over bf16 Bh with per-edge dis[s] + fused bias,
// writes f32 output. 16 lanes/node (4 bf16 cols/lane), 16 nodes/block.
// ---------------------------------------------------------------------------
__global__ __launch_bounds__(256) void agg_out(const uint2* __restrict__ Ah2,
                                               const int* __restrict__ row_ptr,
                                               const int* __restrict__ deg,
                                               const int* __restrict__ srt,
                                               const float* __restrict__ dis,
                                               const float* __restrict__ bias,
                                               float* __restrict__ outp) {
    int sub  = threadIdx.x & 15;
    int node = blockIdx.x * 16 + (threadIdx.x >> 4);
    int beg = row_ptr[node];
    int end = beg + deg[node];
    float di = dis[node];
    uint2 su = Ah2[(size_t)node * 16 + sub];
    float4 acc;
    acc.x = di * lo_f(su.x);
    acc.y = di * hi_f(su.x);
    acc.z = di * lo_f(su.y);
    acc.w = di * hi_f(su.y);
    int j = beg;
    for (; j + 4 <= end; j += 4) {
        int s0 = srt[j], s1 = srt[j + 1], s2 = srt[j + 2], s3 = srt[j + 3];
        float d0 = dis[s0], d1 = dis[s1], d2 = dis[s2], d3 = dis[s3];
        uint2 g0 = Ah2[(size_t)s0 * 16 + sub];
        uint2 g1 = Ah2[(size_t)s1 * 16 + sub];
        uint2 g2 = Ah2[(size_t)s2 * 16 + sub];
        uint2 g3 = Ah2[(size_t)s3 * 16 + sub];
        acc.x = fmaf(d0, lo_f(g0.x), fmaf(d1, lo_f(g1.x), fmaf(d2, lo_f(g2.x), fmaf(d3, lo_f(g3.x), acc.x))));
        acc.y = fmaf(d0, hi_f(g0.x), fmaf(d1, hi_f(g1.x), fmaf(d2, hi_f(g2.x), fmaf(d3, hi_f(g3.x), acc.y))));
        acc.z = fmaf(d0, lo_f(g0.y), fmaf(d1, lo_f(g1.y), fmaf(d2, lo_f(g2.y), fmaf(d3, lo_f(g3.y), acc.z))));
        acc.w = fmaf(d0, hi_f(g0.y), fmaf(d1, hi_f(g1.y), fmaf(d2, hi_f(g2.y), fmaf(d3, hi_f(g3.y), acc.w))));
    }
    for (; j < end; ++j) {
        int s0 = srt[j];
        float d0 = dis[s0];
        uint2 g0 = Ah2[(size_t)s0 * 16 + sub];
        acc.x = fmaf(d0, lo_f(g0.x), acc.x);
        acc.y = fmaf(d0, hi_f(g0.x), acc.y);
        acc.z = fmaf(d0, lo_f(g0.y), acc.z);
        acc.w = fmaf(d0, hi_f(g0.y), acc.w);
    }
    float4 bb = ((const float4*)bias)[sub];
    float4 o;
    o.x = fmaf(di, acc.x, bb.x);
    o.y = fmaf(di, acc.y, bb.y);
    o.z = fmaf(di, acc.z, bb.z);
    o.w = fmaf(di, acc.w, bb.w);
    ((float4*)outp)[(size_t)node * 16 + sub] = o;
}

extern "C" void kernel_launch(void* const* d_in, const int* in_sizes, int n_in,
                              void* d_out, int out_size, void* d_ws, size_t ws_size,
                              hipStream_t stream) {
    const float* x  = (const float*)d_in[0];
    const int*   ei = (const int*)d_in[1];   // [2,E]: src = ei[0:E], dst = ei[E:2E]
    const float* W1 = (const float*)d_in[2];
    const float* b1 = (const float*)d_in[3];
    const float* W2 = (const float*)d_in[4];
    const float* b2 = (const float*)d_in[5];
    float* out = (float*)d_out;
    int E = in_sizes[1] / 2;
    const int* src = ei;
    const int* dst = ei + E;

    int*      ws_i    = (int*)d_ws;
    int*      cursor  = ws_i + O_CURSOR;
    int*      row_ptr = ws_i + O_ROWPTR;
    int*      deg     = ws_i + O_DEG;
    float*    dis     = (float*)(ws_i + O_DIS);
    unsigned* packed  = (unsigned*)(ws_i + O_PACKED);
    int*      srt     = ws_i + O_SRT;
    unsigned* Ah      = (unsigned*)(ws_i + O_AH);
    unsigned* Bh      = (unsigned*)(ws_i + O_BH);

    int nbp = (E + TILE - 1) / TILE;

    hipMemsetAsync(cursor, 0, NBUCK * sizeof(int), stream);
    // K1: binpack (first nbp blocks) || layer-1 gemm blocks [0, G1A)
    pre_gemm1<<<nbp + G1A, 512, 0, stream>>>(src, dst, E, nbp, cursor, packed,
                                             x, W1, Ah);
    // K2: node_sort (first NBUCK blocks) || layer-1 gemm blocks [G1A, G1TOT)
    sort_gemm1<<<NBUCK + (G1TOT - G1A), 512, 0, stream>>>(packed, cursor, row_ptr,
                                                          deg, dis, srt, x, W1, Ah);
    // K3: layer-1 aggregate + ReLU + fused layer-2 gemm -> bf16 Bh
    agg1_gemm2<<<NN / 16, 256, 0, stream>>>((const uint2*)Ah, row_ptr, deg, srt,
                                            dis, b1, W2, Bh);
    // K4: layer-2 aggregate -> f32 out
    agg_out<<<NN / 16, 256, 0, stream>>>((const uint2*)Bh, row_ptr, deg, srt,
                                         dis, b2, out);
}

// Round 2
// 193.093 us; speedup vs baseline: 1.0874x; 1.0392x over previous
//
#include <hip/hip_runtime.h>

#define NN    100000   // N_NODES
#define F     64       // feature dim (= hidden dim)
#define NBUCK 391      // ceil(NN/256) buckets of 256 nodes
#define CAPB  4096     // per-bucket edge capacity (mean 3197, 16-sigma margin)
#define TILE  4096     // edges per binpack tile
#define G1A   1600     // gemm1 blocks placed in K1 (rest overlap node_sort in K2)
#define G1TOT 3125     // NN/32 total gemm1 blocks

// workspace offsets (4-byte elements)
#define O_CURSOR 0          // int[391]
#define O_ROWPTR 512        // int[100000]  absolute index into srt
#define O_DEG    100864     // int[100000]
#define O_DIS    201216     // float[100000]
#define O_PACKED 301568     // uint[391*4096]
#define O_SRT    1903104    // int[391*4096 + 64]
#define O_AH     3504768    // uint[NN*32]: bf16-packed layer-1 A rows (128 B/row)
#define O_BH     6704768    // uint[NN*32]: bf16-packed layer-2 rows dis*(h@W2)

// ---- bf16 pack/unpack (RNE; values finite) --------------------------------
__device__ __forceinline__ unsigned bf_rne(float x) {
    unsigned u = __float_as_uint(x);
    return (u + 0x7FFFu + ((u >> 16) & 1u)) >> 16;
}
__device__ __forceinline__ unsigned pack2(float lo, float hi) {
    return bf_rne(lo) | (bf_rne(hi) << 16);
}
__device__ __forceinline__ float lo_f(unsigned u) { return __uint_as_float(u << 16); }
__device__ __forceinline__ float hi_f(unsigned u) { return __uint_as_float(u & 0xFFFF0000u); }

// ---- shared-memory unions (per-block exclusive) ----------------------------
struct BpSmem {
    int hist[NBUCK], lofs[NBUCK], gbase[NBUCK], lcur[NBUCK];
    int wsum[8];
    unsigned stage[TILE];                     // 16 KB
    unsigned short sbuck[TILE];               // 8 KB
};                                            // 30864 B
union KSmem {
    BpSmem bp;
    float wl[64 * 64];                        // 16 KB
};
struct NsSmem {
    int h[256], lcur[256], wsum[4];
    int stage[CAPB];                          // 16 KB
};                                            // 18448 B
union K2Smem {
    NsSmem ns;
    float wl[64 * 64];                        // 16 KB
};

// ---------------------------------------------------------------------------
// binpack body: tile counting-sort into 391 bucket-strided regions (one
// global atomic per bucket per tile at implicit base b*CAPB).
// packed = (src<<8) | (dst & 255). 512 threads.
// ---------------------------------------------------------------------------
__device__ __forceinline__ void binpack_body(const int* __restrict__ src,
                                             const int* __restrict__ dst, int E,
                                             int* __restrict__ cursor,
                                             unsigned* __restrict__ packed,
                                             int bid, BpSmem& sm) {
    int t  = threadIdx.x;
    int t0 = bid * TILE;
    int n  = min(TILE, E - t0);

    if (t < NBUCK) sm.hist[t] = 0;
    __syncthreads();
    for (int i = t; i < n; i += 512) atomicAdd(&sm.hist[dst[t0 + i] >> 8], 1);
    __syncthreads();
    int lane = t & 63, w = t >> 6;
    int v = (t < NBUCK) ? sm.hist[t] : 0;
    int s = v;
#pragma unroll
    for (int off = 1; off < 64; off <<= 1) {
        int u = __shfl_up(s, off, 64);
        if (lane >= off) s += u;
    }
    if (lane == 63) sm.wsum[w] = s;
    __syncthreads();
    if (t == 0) {
        int run = 0;
#pragma unroll
        for (int i = 0; i < 8; ++i) { int c = sm.wsum[i]; sm.wsum[i] = run; run += c; }
    }
    __syncthreads();
    if (t < NBUCK) {
        int ex = s - v + sm.wsum[w];
        sm.lofs[t] = ex;
        sm.lcur[t] = ex;
        sm.gbase[t] = t * CAPB + (v ? atomicAdd(&cursor[t], v) : 0);
    }
    __syncthreads();
    for (int i = t; i < n; i += 512) {
        int d = dst[t0 + i];
        int b = d >> 8;
        int p = atomicAdd(&sm.lcur[b], 1);
        sm.stage[p] = ((unsigned)src[t0 + i] << 8) | (unsigned)(d & 255);
        sm.sbuck[p] = (unsigned short)b;
    }
    __syncthreads();
    for (int i = t; i < n; i += 512) {
        int b = sm.sbuck[i];
        packed[sm.gbase[b] + (i - sm.lofs[b])] = sm.stage[i];
    }
}

// ---------------------------------------------------------------------------
// gemm body (f32 X): Ah = bf16(X @ W). VALU loop, x broadcast via readlane.
// 512 thr = 8 waves x 4 rows = 32 rows/block. Even lanes pack col pairs.
// ---------------------------------------------------------------------------
__device__ __forceinline__ void gemm_body(const float* __restrict__ X,
                                          const float* __restrict__ W,
                                          unsigned* __restrict__ Ah, int bid,
                                          float* wl) {
    int t = threadIdx.x;
    for (int i = t; i < 64 * 64; i += 512) wl[i] = W[i];
    __syncthreads();
    int lane = t & 63;
    int w    = t >> 6;
    float Wreg[64];
#pragma unroll
    for (int k = 0; k < 64; ++k) Wreg[k] = wl[k * 64 + lane];

    int row0 = bid * 32 + w * 4;
    const float* xp = X + (size_t)row0 * F;
    float xa = xp[lane];
    float xb = xp[64 + lane];
    float xc = xp[128 + lane];
    float xd = xp[192 + lane];
    float a0 = 0.f, a1 = 0.f, a2 = 0.f, a3 = 0.f;
#pragma unroll
    for (int k = 0; k < 64; ++k) {
        float wv = Wreg[k];
        a0 = fmaf(__uint_as_float(__builtin_amdgcn_readlane(__float_as_uint(xa), k)), wv, a0);
        a1 = fmaf(__uint_as_float(__builtin_amdgcn_readlane(__float_as_uint(xb), k)), wv, a1);
        a2 = fmaf(__uint_as_float(__builtin_amdgcn_readlane(__float_as_uint(xc), k)), wv, a2);
        a3 = fmaf(__uint_as_float(__builtin_amdgcn_readlane(__float_as_uint(xd), k)), wv, a3);
    }
    float p0 = __shfl_xor(a0, 1, 64);
    float p1 = __shfl_xor(a1, 1, 64);
    float p2 = __shfl_xor(a2, 1, 64);
    float p3 = __shfl_xor(a3, 1, 64);
    if (!(lane & 1)) {
        int c = lane >> 1;
        Ah[(size_t)(row0 + 0) * 32 + c] = pack2(a0, p0);
        Ah[(size_t)(row0 + 1) * 32 + c] = pack2(a1, p1);
        Ah[(size_t)(row0 + 2) * 32 + c] = pack2(a2, p2);
        Ah[(size_t)(row0 + 3) * 32 + c] = pack2(a3, p3);
    }
}

// ---------------------------------------------------------------------------
// node_sort body: per-bucket LDS counting sort to node order; emits row_ptr
// (absolute), deg, dis = rsqrt(deg+1). srt stays bucket-strided.
// ---------------------------------------------------------------------------
__device__ __forceinline__ void node_sort_body(const unsigned* __restrict__ packed,
                                               const int* __restrict__ cursor,
                                               int* __restrict__ row_ptr,
                                               int* __restrict__ deg,
                                               float* __restrict__ dis,
                                               int* __restrict__ srt,
                                               int b, NsSmem& sm) {
    int t = threadIdx.x;
    int nbase = b << 8;
    int nloc = min(256, NN - nbase);
    int beg = b * CAPB;
    int n = cursor[b];

    if (t < 256) sm.h[t] = 0;
    __syncthreads();
    for (int i = t; i < n; i += 512)
        atomicAdd(&sm.h[packed[beg + i] & 255u], 1);
    __syncthreads();
    int lane = t & 63, w = t >> 6;
    int v = 0, s = 0;
    if (t < 256) { v = sm.h[t]; s = v; }
#pragma unroll
    for (int off = 1; off < 64; off <<= 1) {
        int u = __shfl_up(s, off, 64);
        if (lane >= off) s += u;
    }
    if (t < 256 && lane == 63) sm.wsum[w] = s;
    __syncthreads();
    if (t == 0) {
        int run = 0;
#pragma unroll
        for (int i = 0; i < 4; ++i) { int c = sm.wsum[i]; sm.wsum[i] = run; run += c; }
    }
    __syncthreads();
    if (t < 256) {
        int e0 = s - v + sm.wsum[w];
        sm.lcur[t] = e0;
        if (t < nloc) {
            row_ptr[nbase + t] = beg + e0;
            deg[nbase + t]     = v;
            dis[nbase + t]     = rsqrtf((float)v + 1.0f);   // +1 = self-loop
        }
    }
    __syncthreads();
    for (int i = t; i < n; i += 512) {
        unsigned p = packed[beg + i];
        int pos = atomicAdd(&sm.lcur[p & 255u], 1);
        sm.stage[pos] = (int)(p >> 8);
    }
    __syncthreads();
    for (int i = t; i < n; i += 512) srt[beg + i] = sm.stage[i];
}

// K1: binpack (blocks [0,nbp)) || layer-1 gemm part A (rest). LDS = union.
__global__ __launch_bounds__(512) void pre_gemm1(const int* __restrict__ src,
                                                 const int* __restrict__ dst, int E,
                                                 int nbp, int* __restrict__ cursor,
                                                 unsigned* __restrict__ packed,
                                                 const float* __restrict__ X,
                                                 const float* __restrict__ W1,
                                                 unsigned* __restrict__ Ah) {
    __shared__ KSmem sm;
    if ((int)blockIdx.x < nbp)
        binpack_body(src, dst, E, cursor, packed, blockIdx.x, sm.bp);
    else
        gemm_body(X, W1, Ah, (int)blockIdx.x - nbp, sm.wl);
}

// K2: node_sort (blocks [0,NBUCK)) || layer-1 gemm part B (rest).
__global__ __launch_bounds__(512) void sort_gemm1(const unsigned* __restrict__ packed,
                                                  const int* __restrict__ cursor,
                                                  int* __restrict__ row_ptr,
                                                  int* __restrict__ deg,
                                                  float* __restrict__ dis,
                                                  int* __restrict__ srt,
                                                  const float* __restrict__ X,
                                                  const float* __restrict__ W1,
                                                  unsigned* __restrict__ Ah) {
    __shared__ K2Smem sm;
    if ((int)blockIdx.x < NBUCK)
        node_sort_body(packed, cursor, row_ptr, deg, dis, srt, blockIdx.x, sm.ns);
    else
        gemm_body(X, W1, Ah, G1A + (int)blockIdx.x - NBUCK, sm.wl);
}

// ---------------------------------------------------------------------------
// K3: layer-1 aggregate fused with layer-2 transform.
// 256 thr = 16 nodes x (2 edge-groups x 8 lanes). Each lane owns 8 cols
// (one uint4 = 16 B of the 128 B bf16 row). Groups process interleaved
// edges (stride 2, unroll 4) -> 8 rows in flight per node; combine via
// shfl_xor(8). Epilogue: h @ W2 per wave (4 nodes), writes
// Bh = bf16(dis * (h @ W2)) so K4 needs no per-edge dis loads.
// ---------------------------------------------------------------------------
__global__ __launch_bounds__(256) void agg1_gemm2(const uint4* __restrict__ Ah4,
                                                  const int* __restrict__ row_ptr,
                                                  const int* __restrict__ deg,
                                                  const int* __restrict__ srt,
                                                  const float* __restrict__ dis,
                                                  const float* __restrict__ b1,
                                                  const float* __restrict__ W2,
                                                  unsigned* __restrict__ Bh) {
    __shared__ float wl[64 * 64];                 // W2 staged once per block
    int t = threadIdx.x;
    for (int i = t; i < 1024; i += 256)
        ((float4*)wl)[i] = ((const float4*)W2)[i];
    __syncthreads();

    int sub  = t & 7;            // col chunk: cols [8*sub, 8*sub+8)
    int grp  = (t >> 3) & 1;     // edge group
    int node = blockIdx.x * 16 + (t >> 4);
    int beg = row_ptr[node];
    int end = beg + deg[node];
    float di = dis[node];

    float a0, a1, a2, a3, a4, a5, a6, a7;
    uint4 su = Ah4[(size_t)node * 8 + sub];
    if (grp == 0) {
        a0 = di * lo_f(su.x); a1 = di * hi_f(su.x);
        a2 = di * lo_f(su.y); a3 = di * hi_f(su.y);
        a4 = di * lo_f(su.z); a5 = di * hi_f(su.z);
        a6 = di * lo_f(su.w); a7 = di * hi_f(su.w);
    } else {
        a0 = a1 = a2 = a3 = a4 = a5 = a6 = a7 = 0.f;
    }

    int j = beg + grp;
    for (; j + 6 < end; j += 8) {
        int s0 = srt[j], s1 = srt[j + 2], s2 = srt[j + 4], s3 = srt[j + 6];
        float d0 = dis[s0], d1 = dis[s1], d2 = dis[s2], d3 = dis[s3];
        uint4 g0 = Ah4[(size_t)s0 * 8 + sub];
        uint4 g1 = Ah4[(size_t)s1 * 8 + sub];
        uint4 g2 = Ah4[(size_t)s2 * 8 + sub];
        uint4 g3 = Ah4[(size_t)s3 * 8 + sub];
        a0 = fmaf(d0, lo_f(g0.x), fmaf(d1, lo_f(g1.x), fmaf(d2, lo_f(g2.x), fmaf(d3, lo_f(g3.x), a0))));
        a1 = fmaf(d0, hi_f(g0.x), fmaf(d1, hi_f(g1.x), fmaf(d2, hi_f(g2.x), fmaf(d3, hi_f(g3.x), a1))));
        a2 = fmaf(d0, lo_f(g0.y), fmaf(d1, lo_f(g1.y), fmaf(d2, lo_f(g2.y), fmaf(d3, lo_f(g3.y), a2))));
        a3 = fmaf(d0, hi_f(g0.y), fmaf(d1, hi_f(g1.y), fmaf(d2, hi_f(g2.y), fmaf(d3, hi_f(g3.y), a3))));
        a4 = fmaf(d0, lo_f(g0.z), fmaf(d1, lo_f(g1.z), fmaf(d2, lo_f(g2.z), fmaf(d3, lo_f(g3.z), a4))));
        a5 = fmaf(d0, hi_f(g0.z), fmaf(d1, hi_f(g1.z), fmaf(d2, hi_f(g2.z), fmaf(d3, hi_f(g3.z), a5))));
        a6 = fmaf(d0, lo_f(g0.w), fmaf(d1, lo_f(g1.w), fmaf(d2, lo_f(g2.w), fmaf(d3, lo_f(g3.w), a6))));
        a7 = fmaf(d0, hi_f(g0.w), fmaf(d1, hi_f(g1.w), fmaf(d2, hi_f(g2.w), fmaf(d3, hi_f(g3.w), a7))));
    }
    for (; j + 2 < end; j += 4) {
        int s0 = srt[j], s1 = srt[j + 2];
        float d0 = dis[s0], d1 = dis[s1];
        uint4 g0 = Ah4[(size_t)s0 * 8 + sub];
        uint4 g1 = Ah4[(size_t)s1 * 8 + sub];
        a0 = fmaf(d0, lo_f(g0.x), fmaf(d1, lo_f(g1.x), a0));
        a1 = fmaf(d0, hi_f(g0.x), fmaf(d1, hi_f(g1.x), a1));
        a2 = fmaf(d0, lo_f(g0.y), fmaf(d1, lo_f(g1.y), a2));
        a3 = fmaf(d0, hi_f(g0.y), fmaf(d1, hi_f(g1.y), a3));
        a4 = fmaf(d0, lo_f(g0.z), fmaf(d1, lo_f(g1.z), a4));
        a5 = fmaf(d0, hi_f(g0.z), fmaf(d1, hi_f(g1.z), a5));
        a6 = fmaf(d0, lo_f(g0.w), fmaf(d1, lo_f(g1.w), a6));
        a7 = fmaf(d0, hi_f(g0.w), fmaf(d1, hi_f(g1.w), a7));
    }
    for (; j < end; j += 2) {
        int s0 = srt[j];
        float d0 = dis[s0];
        uint4 g0 = Ah4[(size_t)s0 * 8 + sub];
        a0 = fmaf(d0, lo_f(g0.x), a0);
        a1 = fmaf(d0, hi_f(g0.x), a1);
        a2 = fmaf(d0, lo_f(g0.y), a2);
        a3 = fmaf(d0, hi_f(g0.y), a3);
        a4 = fmaf(d0, lo_f(g0.z), a4);
        a5 = fmaf(d0, hi_f(g0.z), a5);
        a6 = fmaf(d0, lo_f(g0.w), a6);
        a7 = fmaf(d0, hi_f(g0.w), a7);
    }
    // combine the two edge-groups (lane ^ 8 within each 16-lane node slice)
    a0 += __shfl_xor(a0, 8, 64); a1 += __shfl_xor(a1, 8, 64);
    a2 += __shfl_xor(a2, 8, 64); a3 += __shfl_xor(a3, 8, 64);
    a4 += __shfl_xor(a4, 8, 64); a5 += __shfl_xor(a5, 8, 64);
    a6 += __shfl_xor(a6, 8, 64); a7 += __shfl_xor(a7, 8, 64);

    float4 bb0 = ((const float4*)b1)[2 * sub];
    float4 bb1 = ((const float4*)b1)[2 * sub + 1];
    float o0 = fmaxf(fmaf(di, a0, bb0.x), 0.f);
    float o1 = fmaxf(fmaf(di, a1, bb0.y), 0.f);
    float o2 = fmaxf(fmaf(di, a2, bb0.z), 0.f);
    float o3 = fmaxf(fmaf(di, a3, bb0.w), 0.f);
    float o4 = fmaxf(fmaf(di, a4, bb1.x), 0.f);
    float o5 = fmaxf(fmaf(di, a5, bb1.y), 0.f);
    float o6 = fmaxf(fmaf(di, a6, bb1.z), 0.f);
    float o7 = fmaxf(fmaf(di, a7, bb1.w), 0.f);
    unsigned pk0 = pack2(o0, o1);
    unsigned pk1 = pack2(o2, o3);
    unsigned pk2 = pack2(o4, o5);
    unsigned pk3 = pack2(o6, o7);

    // ---- fused h @ W2 (per wave: 4 nodes; lane = output col) ---------------
    int lane = t & 63;
    float c0 = 0.f, c1 = 0.f, c2 = 0.f, c3 = 0.f;
#pragma unroll
    for (int l8 = 0; l8 < 8; ++l8) {
#define STEP(PK, P)                                                        \
        {                                                                  \
            int k0 = l8 * 8 + 2 * (P);                                     \
            float w0 = wl[k0 * 64 + lane];                                 \
            float w1 = wl[k0 * 64 + 64 + lane];                            \
            unsigned u0 = __builtin_amdgcn_readlane(PK, l8);               \
            unsigned u1 = __builtin_amdgcn_readlane(PK, 16 + l8);          \
            unsigned u2 = __builtin_amdgcn_readlane(PK, 32 + l8);          \
            unsigned u3 = __builtin_amdgcn_readlane(PK, 48 + l8);          \
            c0 = fmaf(lo_f(u0), w0, c0); c0 = fmaf(hi_f(u0), w1, c0);      \
            c1 = fmaf(lo_f(u1), w0, c1); c1 = fmaf(hi_f(u1), w1, c1);      \
            c2 = fmaf(lo_f(u2), w0, c2); c2 = fmaf(hi_f(u2), w1, c2);      \
            c3 = fmaf(lo_f(u3), w0, c3); c3 = fmaf(hi_f(u3), w1, c3);      \
        }
        STEP(pk0, 0)
        STEP(pk1, 1)
        STEP(pk2, 2)
        STEP(pk3, 3)
#undef STEP
    }
    // pre-scale by dis[node] before bf16 pack (node n of wave at lane 16n)
    float dA = __shfl(di, 0, 64);
    float dB = __shfl(di, 16, 64);
    float dC = __shfl(di, 32, 64);
    float dD = __shfl(di, 48, 64);
    c0 *= dA; c1 *= dB; c2 *= dC; c3 *= dD;
    float q0 = __shfl_xor(c0, 1, 64);
    float q1 = __shfl_xor(c1, 1, 64);
    float q2 = __shfl_xor(c2, 1, 64);
    float q3 = __shfl_xor(c3, 1, 64);
    if (!(lane & 1)) {
        int c = lane >> 1;
        int n0 = blockIdx.x * 16 + (t >> 6) * 4;
        Bh[(size_t)(n0 + 0) * 32 + c] = pack2(c0, q0);
        Bh[(size_t)(n0 + 1) * 32 + c] = pack2(c1, q1);
        Bh[(size_t)(n0 + 2) * 32 + c] = pack2(c2, q2);
        Bh[(size_t)(n0 + 3) * 32 + c] = pack2(c3, q3);
    }
}

// ---------------------------------------------------------------------------
// K4: layer-2 aggregate over pre-scaled bf16 Bh rows (no per-edge dis!),
// same 16-node x (2 grp x 8 lane) structure, f32 float4 output.
// ---------------------------------------------------------------------------
__global__ __launch_bounds__(256) void agg_out(const uint4* __restrict__ Bs4,
                                               const int* __restrict__ row_ptr,
                                               const int* __restrict__ deg,
                                               const int* __restrict__ srt,
                                               const float* __restrict__ dis,
                                               const float* __restrict__ bias,
                                               float* __restrict__ outp) {
    int t = threadIdx.x;
    int sub  = t & 7;
    int grp  = (t >> 3) & 1;
    int node = blockIdx.x * 16 + (t >> 4);
    int beg = row_ptr[node];
    int end = beg + deg[node];
    float di = dis[node];

    float a0, a1, a2, a3, a4, a5, a6, a7;
    uint4 su = Bs4[(size_t)node * 8 + sub];     // already dis-scaled
    if (grp == 0) {
        a0 = lo_f(su.x); a1 = hi_f(su.x);
        a2 = lo_f(su.y); a3 = hi_f(su.y);
        a4 = lo_f(su.z); a5 = hi_f(su.z);
        a6 = lo_f(su.w); a7 = hi_f(su.w);
    } else {
        a0 = a1 = a2 = a3 = a4 = a5 = a6 = a7 = 0.f;
    }

    int j = beg + grp;
    for (; j + 6 < end; j += 8) {
        int s0 = srt[j], s1 = srt[j + 2], s2 = srt[j + 4], s3 = srt[j + 6];
        uint4 g0 = Bs4[(size_t)s0 * 8 + sub];
        uint4 g1 = Bs4[(size_t)s1 * 8 + sub];
        uint4 g2 = Bs4[(size_t)s2 * 8 + sub];
        uint4 g3 = Bs4[(size_t)s3 * 8 + sub];
        a0 += (lo_f(g0.x) + lo_f(g1.x)) + (lo_f(g2.x) + lo_f(g3.x));
        a1 += (hi_f(g0.x) + hi_f(g1.x)) + (hi_f(g2.x) + hi_f(g3.x));
        a2 += (lo_f(g0.y) + lo_f(g1.y)) + (lo_f(g2.y) + lo_f(g3.y));
        a3 += (hi_f(g0.y) + hi_f(g1.y)) + (hi_f(g2.y) + hi_f(g3.y));
        a4 += (lo_f(g0.z) + lo_f(g1.z)) + (lo_f(g2.z) + lo_f(g3.z));
        a5 += (hi_f(g0.z) + hi_f(g1.z)) + (hi_f(g2.z) + hi_f(g3.z));
        a6 += (lo_f(g0.w) + lo_f(g1.w)) + (lo_f(g2.w) + lo_f(g3.w));
        a7 += (hi_f(g0.w) + hi_f(g1.w)) + (hi_f(g2.w) + hi_f(g3.w));
    }
    for (; j + 2 < end; j += 4) {
        int s0 = srt[j], s1 = srt[j + 2];
        uint4 g0 = Bs4[(size_t)s0 * 8 + sub];
        uint4 g1 = Bs4[(size_t)s1 * 8 + sub];
        a0 += lo_f(g0.x) + lo_f(g1.x);
        a1 += hi_f(g0.x) + hi_f(g1.x);
        a2 += lo_f(g0.y) + lo_f(g1.y);
        a3 += hi_f(g0.y) + hi_f(g1.y);
        a4 += lo_f(g0.z) + lo_f(g1.z);
        a5 += hi_f(g0.z) + hi_f(g1.z);
        a6 += lo_f(g0.w) + lo_f(g1.w);
        a7 += hi_f(g0.w) + hi_f(g1.w);
    }
    for (; j < end; j += 2) {
        int s0 = srt[j];
        uint4 g0 = Bs4[(size_t)s0 * 8 + sub];
        a0 += lo_f(g0.x); a1 += hi_f(g0.x);
        a2 += lo_f(g0.y); a3 += hi_f(g0.y);
        a4 += lo_f(g0.z); a5 += hi_f(g0.z);
        a6 += lo_f(g0.w); a7 += hi_f(g0.w);
    }
    a0 += __shfl_xor(a0, 8, 64); a1 += __shfl_xor(a1, 8, 64);
    a2 += __shfl_xor(a2, 8, 64); a3 += __shfl_xor(a3, 8, 64);
    a4 += __shfl_xor(a4, 8, 64); a5 += __shfl_xor(a5, 8, 64);
    a6 += __shfl_xor(a6, 8, 64); a7 += __shfl_xor(a7, 8, 64);

    float4 bb0 = ((const float4*)bias)[2 * sub];
    float4 bb1 = ((const float4*)bias)[2 * sub + 1];
    float4 o;
    if (grp == 0) {
        o.x = fmaf(di, a0, bb0.x);
        o.y = fmaf(di, a1, bb0.y);
        o.z = fmaf(di, a2, bb0.z);
        o.w = fmaf(di, a3, bb0.w);
        ((float4*)outp)[(size_t)node * 16 + 2 * sub] = o;
    } else {
        o.x = fmaf(di, a4, bb1.x);
        o.y = fmaf(di, a5, bb1.y);
        o.z = fmaf(di, a6, bb1.z);
        o.w = fmaf(di, a7, bb1.w);
        ((float4*)outp)[(size_t)node * 16 + 2 * sub + 1] = o;
    }
}

extern "C" void kernel_launch(void* const* d_in, const int* in_sizes, int n_in,
                              void* d_out, int out_size, void* d_ws, size_t ws_size,
                              hipStream_t stream) {
    const float* x  = (const float*)d_in[0];
    const int*   ei = (const int*)d_in[1];   // [2,E]: src = ei[0:E], dst = ei[E:2E]
    const float* W1 = (const float*)d_in[2];
    const float* b1 = (const float*)d_in[3];
    const float* W2 = (const float*)d_in[4];
    const float* b2 = (const float*)d_in[5];
    float* out = (float*)d_out;
    int E = in_sizes[1] / 2;
    const int* src = ei;
    const int* dst = ei + E;

    int*      ws_i    = (int*)d_ws;
    int*      cursor  = ws_i + O_CURSOR;
    int*      row_ptr = ws_i + O_ROWPTR;
    int*      deg     = ws_i + O_DEG;
    float*    dis     = (float*)(ws_i + O_DIS);
    unsigned* packed  = (unsigned*)(ws_i + O_PACKED);
    int*      srt     = ws_i + O_SRT;
    unsigned* Ah      = (unsigned*)(ws_i + O_AH);
    unsigned* Bh      = (unsigned*)(ws_i + O_BH);

    int nbp = (E + TILE - 1) / TILE;

    hipMemsetAsync(cursor, 0, NBUCK * sizeof(int), stream);
    // K1: binpack (first nbp blocks) || layer-1 gemm blocks [0, G1A)
    pre_gemm1<<<nbp + G1A, 512, 0, stream>>>(src, dst, E, nbp, cursor, packed,
                                             x, W1, Ah);
    // K2: node_sort (first NBUCK blocks) || layer-1 gemm blocks [G1A, G1TOT)
    sort_gemm1<<<NBUCK + (G1TOT - G1A), 512, 0, stream>>>(packed, cursor, row_ptr,
                                                          deg, dis, srt, x, W1, Ah);
    // K3: layer-1 aggregate + ReLU + fused layer-2 gemm -> pre-scaled bf16 Bh
    agg1_gemm2<<<NN / 16, 256, 0, stream>>>((const uint4*)Ah, row_ptr, deg, srt,
                                            dis, b1, W2, Bh);
    // K4: layer-2 aggregate -> f32 out
    agg_out<<<NN / 16, 256, 0, stream>>>((const uint4*)Bh, row_ptr, deg, srt,
                                         dis, b2, out);
}